// Round 13
// baseline (155.003 us; speedup 1.0000x reference)
//
#include <hip/hip_runtime.h>
#include <hip/hip_bf16.h>
#include <math.h>

// TriangleAttention — round 19: 8-wave blocks, head-split across wave-groups.
// r18's fusion left a latency-bound kernel at 2 waves/SIMD (grid 512 x 4-wave
// blocks, occupancy 17.6%). This round doubles TLP at constant total work:
//   block 512 = 2 wave-groups; group wg handles heads {2wg, 2wg+1} over all
//   256 query rows; LN done once by group 0 and shared (znl LDS, 1 barrier);
//   per-group KSH/VT buffers; after the head loop group 1 spills acc_out to
//   LDS (overlaying dead znl/KSH/VT, stride-68 floats -> 2-way conflicts only),
//   group 0 adds + bo and stores. LDS 70.1 KB -> 2 blocks/CU -> 4 waves/SIMD.
// __launch_bounds__(512,4): VGPR budget 128 >= ~90 needed (r7 clamp math).
// HAZARD RULES (r10-r14): inline asm never reads an MFMA dest directly — a
// compiler VALU op in between (s*L2E mul / ag+bg add / lacc add+mul) absorbs
// the wait-states. ds_write/compiler-VALU reads of MFMA dests are safe.
// BAN LIST (r7-8): __builtin_amdgcn_exp2f/rcpf.
// CANARY: VGPR <= 128 (clamp), WRITE ~32.8 MB (spill), absmax <= 0.0155.
// B=2, L=256, D=64, H=4, Dh=16.
//
// 16x16x32 layouts (verified r2-5):  A[m=lane&15][k=quad*8+u],
//   B[k=quad*8+u][n=lane&15], C/D: col=lane&15, row=quad*4+reg.
// 16x16x16 layouts (verified r14): A[m=lane&15][k=quad*4+u],
//   B[k=quad*4+u][n=lane&15], C/D identical to above.

typedef __attribute__((ext_vector_type(4))) float f32x4;
typedef __attribute__((ext_vector_type(8))) short s16x8;
typedef __attribute__((ext_vector_type(4))) short s16x4;

#define MFMA16(a, b, c) __builtin_amdgcn_mfma_f32_16x16x32_bf16((a), (b), (c), 0, 0, 0)

__device__ __forceinline__ f32x4 mfma16b(s16x4 a, s16x4 b, f32x4 c) {
#if __has_builtin(__builtin_amdgcn_mfma_f32_16x16x16bf16_1k)
    return __builtin_amdgcn_mfma_f32_16x16x16bf16_1k(a, b, c, 0, 0, 0);
#elif __has_builtin(__builtin_amdgcn_mfma_f32_16x16x16_bf16)
    return __builtin_amdgcn_mfma_f32_16x16x16_bf16(a, b, c, 0, 0, 0);
#else
    f32x4 d;
    asm volatile("s_nop 1\n\t"
                 "v_mfma_f32_16x16x16_bf16 %0, %1, %2, %3\n\t"
                 "s_nop 7\n\t"
                 "s_nop 7"
                 : "=v"(d) : "v"(a), "v"(b), "v"(c));
    return d;
#endif
}

__device__ __forceinline__ float exp2a(float x) {   // raw v_exp_f32 (input MUST
    float r;                                        // be VALU-produced, not MFMA)
    asm("v_exp_f32 %0, %1" : "=v"(r) : "v"(x));
    return r;
}
__device__ __forceinline__ float rcpa(float x) {    // raw v_rcp_f32 (same rule)
    float r;
    asm("v_rcp_f32 %0, %1" : "=v"(r) : "v"(x));
    return r;
}

__device__ __forceinline__ unsigned pk2(float a, float b) {   // 2xf32 -> packed bf16x2 (RNE)
    union { __hip_bfloat162 h; unsigned u; } c;
    float2 t; t.x = a; t.y = b;
    c.h = __float22bfloat162_rn(t);
    return c.u;
}
__device__ __forceinline__ s16x8 cvt8(const float* p) {  // 8 fp32 -> bf16x8
    union { unsigned u[4]; s16x8 v; } r;
    r.u[0] = pk2(p[0], p[1]); r.u[1] = pk2(p[2], p[3]);
    r.u[2] = pk2(p[4], p[5]); r.u[3] = pk2(p[6], p[7]);
    return r.v;
}
__device__ __forceinline__ s16x4 cvt4(const float* p) {  // 4 fp32 -> bf16x4
    union { unsigned u[2]; s16x4 v; } r;
    r.u[0] = pk2(p[0], p[1]); r.u[1] = pk2(p[2], p[3]);
    return r.v;
}

// LDS map (shorts).
//   ZNL: LN'd rows, slice per row-block (wl): wl*4096; row lr at
//        (lr>>4)*1024 + (lr&15)*64, gq-swizzled (r6-verified layout).
//   Per wave-group wg: KSH [256 pos][20 pad] at 16384+wg*9344, VT [16][264] after.
//   Reduction overlay (post-head-loop): f32 [256 rows][stride 68] at base 0
//   (69632 B <= 70144 B allocation; znl/KSH/VT all dead by then).
static constexpr int ZNL = 0;           // 4*4096 = 16384 sh
static constexpr int KSHB = 16384;      // + wg*9344
static constexpr int LDS_EL = 35072;    // 70144 B -> 2 blocks/CU at block 512

__global__ __launch_bounds__(512, 4)
void ka_all(const float* __restrict__ z, const float* __restrict__ ln_s,
            const float* __restrict__ ln_b, const float* __restrict__ Wq,
            const float* __restrict__ Wk, const float* __restrict__ Wv,
            const float* __restrict__ Wg, const float* __restrict__ bg,
            const float* __restrict__ Wo, const float* __restrict__ bo,
            float* __restrict__ out)
{
    __shared__ __align__(16) short lds[LDS_EL];
    const int tid = threadIdx.x, lane = tid & 63, w = tid >> 6;
    const int wg = w >> 2, wl = w & 3;             // group, wave-in-group
    const int n16 = lane & 15, quad = lane >> 4;
    const int bl = blockIdx.x;
    const int wsl = wl * 4096;                     // znl slice for this row-block
    const int wrows = wl * 64;                     // query rows wl*64..+64
    const int KSHg = KSHB + wg * 9344;
    const int VTg  = KSHg + 5120;

    // ---- LN once per row, by group 0 only (thread tid<256 = row bl*256+tid) ----
    if (w < 4) {
        float zn[64];
        const float4* zp4 = (const float4*)(z + ((size_t)bl * 256 + tid) * 64);
        #pragma unroll
        for (int gq = 0; gq < 16; ++gq) {
            float4 v4 = zp4[gq];
            zn[gq * 4 + 0] = v4.x; zn[gq * 4 + 1] = v4.y;
            zn[gq * 4 + 2] = v4.z; zn[gq * 4 + 3] = v4.w;
        }
        float mu = 0.f;
        #pragma unroll
        for (int k = 0; k < 64; ++k) mu += zn[k];
        mu *= (1.f / 64.f);
        float va = 0.f;
        #pragma unroll
        for (int k = 0; k < 64; ++k) { float d = zn[k] - mu; va += d * d; }
        const float rs = rsqrtf(va * (1.f / 64.f) + 1e-5f);
        #pragma unroll
        for (int k = 0; k < 64; ++k) zn[k] = (zn[k] - mu) * rs * ln_s[k] + ln_b[k];
        const int lr = lane;
        #pragma unroll
        for (int gq = 0; gq < 8; ++gq) {
            union { unsigned u[4]; s16x8 v; } pkv;
            pkv.u[0] = pk2(zn[gq * 8 + 0], zn[gq * 8 + 1]);
            pkv.u[1] = pk2(zn[gq * 8 + 2], zn[gq * 8 + 3]);
            pkv.u[2] = pk2(zn[gq * 8 + 4], zn[gq * 8 + 5]);
            pkv.u[3] = pk2(zn[gq * 8 + 6], zn[gq * 8 + 7]);
            *(s16x8*)&lds[ZNL + wsl + (lr >> 4) * 1024 + (lr & 15) * 64
                          + ((gq ^ (lr & 7)) * 8)] = pkv.v;
        }
    }
    __syncthreads();   // znl visible to both groups (read-only hereafter)

    constexpr float QS  = 0.25f;                            // 1/sqrt(Dh); log2e at exp
    constexpr float L2E = 1.44269504088896340736f;
    s16x4 ones4;                                            // bf16 1.0 x4
    {
        union { unsigned u[2]; s16x4 v; } c;
        c.u[0] = 0x3F803F80u; c.u[1] = 0x3F803F80u;
        ones4 = c.v;
    }

    f32x4 acc_out[4][4];                           // [qt][nt], over this group's heads
    #pragma unroll
    for (int qt = 0; qt < 4; ++qt)
        #pragma unroll
        for (int nt = 0; nt < 4; ++nt) acc_out[qt][nt] = {};

    for (int hh = 0; hh < 2; ++hh) {
        const int h = wg * 2 + hh;
        // ---- W head-slice frags (A for Q/K/G-transposed, B for V) ----
        s16x8 bq[2], bk[2], bv[2], bgf[2];
        #pragma unroll
        for (int ks = 0; ks < 2; ++ks) {
            size_t off = (size_t)(h * 16 + n16) * 64 + ks * 32 + quad * 8;
            bq[ks] = cvt8(Wq + off);  bk[ks] = cvt8(Wk + off);
            bv[ks] = cvt8(Wv + off);  bgf[ks] = cvt8(Wg + off);
        }
        const float4 bg4 = *(const float4*)(bg + h * 16 + quad * 4);

        float g4t[4][4];
        s16x4 qa4[4];                              // Q^T B-frags, in-register
        #pragma unroll
        for (int t = 0; t < 4; ++t) {              // projections for tile t
            s16x8 zn0 = *(const s16x8*)&lds[ZNL + wsl + t * 1024 + n16 * 64
                                            + ((quad ^ (n16 & 7)) * 8)];
            s16x8 zn1 = *(const s16x8*)&lds[ZNL + wsl + t * 1024 + n16 * 64
                                            + (((4 + quad) ^ (n16 & 7)) * 8)];
            f32x4 aq = {}, ak = {}, av = {}, ag = {};
            aq = MFMA16(bq[0], zn0, aq);  aq = MFMA16(bq[1], zn1, aq);   // Q^T
            ak = MFMA16(bk[0], zn0, ak);  ak = MFMA16(bk[1], zn1, ak);   // K^T
            ag = MFMA16(bgf[0], zn0, ag); ag = MFMA16(bgf[1], zn1, ag);  // G^T
            av = MFMA16(zn0, bv[0], av);  av = MFMA16(zn1, bv[1], av);   // V
            {   // Q^T (scaled) -> in-register B-frag: Q^T[dh=quad*4+r][i=n16]
                union { unsigned u[2]; s16x4 v; } q;
                q.u[0] = pk2(aq[0] * QS, aq[1] * QS);
                q.u[1] = pk2(aq[2] * QS, aq[3] * QS);
                qa4[t] = q.v;
            }
            {   // K^T -> KSHg[pos][dh] (stride 20, conflict-free b64 frags)
                uint2 p = {pk2(ak[0], ak[1]), pk2(ak[2], ak[3])};
                *(uint2*)&lds[KSHg + (wrows + t * 16 + n16) * 20 + quad * 4] = p;
            }
            {   // V -> VTg[dh][pos]
                uint2 p = {pk2(av[0], av[1]), pk2(av[2], av[3])};
                *(uint2*)&lds[VTg + n16 * 264 + (wrows + t * 16 + quad * 4)] = p;
            }
            #pragma unroll
            for (int r = 0; r < 4; ++r) {           // gate (pos=n16, dh=q*4+r)
                float x = ag[r] + bg4[r];           // VALU add absorbs MFMA hazard
                g4t[t][r] = rcpa(1.f + exp2a(x * -L2E));
            }
        }
        __syncthreads();   // KSHg/VTg for this head visible across the group

        // ---- attention (16x16x16): S^T = K@Q^T; P in-register; O^T = V^T@P^T;
        //      l = ones@P^T on the matrix pipe ----
        f32x4 o4[4], lacc[4];
        #pragma unroll
        for (int qt = 0; qt < 4; ++qt) { o4[qt] = {}; lacc[qt] = {}; }
        const int kbase = KSHg + n16 * 20 + quad * 4;   // + jt*320
        const int vbase = VTg + n16 * 264 + quad * 4;   // + jt*16
        for (int ch = 0; ch < 8; ++ch) {                // 32 keys per chunk
            #pragma unroll
            for (int jtl = 0; jtl < 2; ++jtl) {
                const int jt = ch * 2 + jtl;
                s16x4 kf = *(const s16x4*)&lds[kbase + jt * 320];
                s16x4 vf = *(const s16x4*)&lds[vbase + jt * 16];
                #pragma unroll
                for (int qt = 0; qt < 4; ++qt) {
                    f32x4 zc = {};
                    f32x4 s = mfma16b(kf, qa4[qt], zc);  // S^T: reg r = key q*4+r, col i=n16
                    // v_mul absorbs the MFMA->asm hazard.
                    float e0 = exp2a(s[0] * L2E), e1 = exp2a(s[1] * L2E);
                    float e2 = exp2a(s[2] * L2E), e3 = exp2a(s[3] * L2E);
                    union { unsigned u[2]; s16x4 v; } pb;
                    pb.u[0] = pk2(e0, e1); pb.u[1] = pk2(e2, e3);
                    o4[qt]   = mfma16b(vf, pb.v, o4[qt]);      // O^T: col=i, row=dh
                    lacc[qt] = mfma16b(ones4, pb.v, lacc[qt]); // l[i], all rows
                }
            }
        }

        // ---- per-head epilogue: gate+normalize -> bf16 -> Wo MFMA accumulate.
        // The gated O^T fragment (col=i=n16, row=dh=quad*4+r) IS the B-frag
        // B[k=dh][n=i] for out_tile = Wo_slice @ GO^T.
        s16x4 goB[4];
        #pragma unroll
        for (int qt = 0; qt < 4; ++qt) {
            const float l = (lacc[qt][0] + lacc[qt][1]) * 0.5f;  // VALU ops absorb hazard
            const float inv = rcpa(l);
            float g0 = g4t[qt][0] * o4[qt][0] * inv;
            float g1 = g4t[qt][1] * o4[qt][1] * inv;
            float g2 = g4t[qt][2] * o4[qt][2] * inv;
            float g3 = g4t[qt][3] * o4[qt][3] * inv;
            union { unsigned u[2]; s16x4 v; } pb;
            pb.u[0] = pk2(g0, g1); pb.u[1] = pk2(g2, g3);
            goB[qt] = pb.v;
        }
        #pragma unroll
        for (int nt = 0; nt < 4; ++nt) {
            // Wo A-frag: A[m=outd local=n16][k=dh=quad*4+u] for tile nt, head h
            s16x4 wof = cvt4(Wo + (size_t)(nt * 16 + n16) * 64 + h * 16 + quad * 4);
            #pragma unroll
            for (int qt = 0; qt < 4; ++qt)
                acc_out[qt][nt] = mfma16b(wof, goB[qt], acc_out[qt][nt]);
        }
        __syncthreads();   // KSHg/VTg reads done before next head's proj writes
                           // (final iteration: before the reduction overlay)
    }

    // ---- cross-group reduction in LDS (overlay; stride 68 floats = 2-way max) ----
    float* red = (float*)lds;
    if (wg == 1) {
        #pragma unroll
        for (int qt = 0; qt < 4; ++qt)
            #pragma unroll
            for (int nt = 0; nt < 4; ++nt)
                *(f32x4*)&red[(wrows + qt * 16 + n16) * 68 + nt * 16 + quad * 4] =
                    acc_out[qt][nt];   // ds_write of MFMA dest: compiler-fenced
    }
    __syncthreads();
    if (wg == 0) {
        #pragma unroll
        for (int nt = 0; nt < 4; ++nt) {
            const float4 b4 = *(const float4*)(bo + nt * 16 + quad * 4);
            f32x4 b4v; b4v[0] = b4.x; b4v[1] = b4.y; b4v[2] = b4.z; b4v[3] = b4.w;
            #pragma unroll
            for (int qt = 0; qt < 4; ++qt) {
                f32x4 o = *(f32x4*)&red[(wrows + qt * 16 + n16) * 68 + nt * 16 + quad * 4];
                f32x4 v = acc_out[qt][nt] + o + b4v;
                *(f32x4*)&out[((size_t)bl * 256 + wrows + qt * 16 + n16) * 64
                              + nt * 16 + quad * 4] = v;
            }
        }
    }
}

extern "C" void kernel_launch(void* const* d_in, const int* in_sizes, int n_in,
                              void* d_out, int out_size, void* d_ws, size_t ws_size,
                              hipStream_t stream) {
    const float* z  = (const float*)d_in[0];
    const float* ls = (const float*)d_in[1];
    const float* lb = (const float*)d_in[2];
    const float* Wq = (const float*)d_in[3];
    const float* Wk = (const float*)d_in[4];
    const float* Wv = (const float*)d_in[5];
    const float* Wg = (const float*)d_in[6];
    const float* bg = (const float*)d_in[7];
    const float* Wo = (const float*)d_in[8];
    const float* bo = (const float*)d_in[9];
    float* out = (float*)d_out;

    hipLaunchKernelGGL(ka_all, dim3(512), dim3(512), 0, stream,
                       z, ls, lb, Wq, Wk, Wv, Wg, bg, Wo, bo, out);
}

// Round 14
// 151.493 us; speedup vs baseline: 1.0232x; 1.0232x over previous
//
#include <hip/hip_runtime.h>
#include <hip/hip_bf16.h>
#include <math.h>

// TriangleAttention — round 20: r19's 8-wave head-split structure with the
// launch-bounds clamp removed. EMPIRICAL RULE (r7 + r19, two block sizes):
// __launch_bounds__(*, >=4) clamps the allocator to 64 VGPRs -> scratch spill
// (r19: VGPR=64, WRITE 67 MB, 77 µs). Args 2/3 never clamp (r11/r17/r18).
// Here: __launch_bounds__(512,3). LDS 70144 B -> 2 blocks/CU -> 4 waves/SIMD
// provided VGPR <= 128 (kernel needs ~90-100; allocator lands there unforced).
//   block 512 = 2 wave-groups; group wg handles heads {2wg, 2wg+1} over all
//   256 query rows; LN once by group 0, shared via znl LDS (1 barrier);
//   per-group KSH/VT; after the head loop group 1 spills acc_out to LDS
//   (overlay of dead znl/KSH/VT, stride-68 floats -> 2-way conflicts only),
//   group 0 adds + bo and stores.
// HAZARD RULES (r10-r14): inline asm never reads an MFMA dest directly — a
// compiler VALU op in between (s*L2E mul / ag+bg add / lacc add+mul) absorbs
// the wait-states. ds_write/compiler-VALU reads of MFMA dests are safe.
// BAN LIST (r7-8): __builtin_amdgcn_exp2f/rcpf. launch_bounds arg >= 4.
// CANARY: VGPR <= 128 (clamp), WRITE ~33 MB (spill), absmax <= 0.0155.
// B=2, L=256, D=64, H=4, Dh=16.
//
// 16x16x32 layouts (verified r2-5):  A[m=lane&15][k=quad*8+u],
//   B[k=quad*8+u][n=lane&15], C/D: col=lane&15, row=quad*4+reg.
// 16x16x16 layouts (verified r14): A[m=lane&15][k=quad*4+u],
//   B[k=quad*4+u][n=lane&15], C/D identical to above.

typedef __attribute__((ext_vector_type(4))) float f32x4;
typedef __attribute__((ext_vector_type(8))) short s16x8;
typedef __attribute__((ext_vector_type(4))) short s16x4;

#define MFMA16(a, b, c) __builtin_amdgcn_mfma_f32_16x16x32_bf16((a), (b), (c), 0, 0, 0)

__device__ __forceinline__ f32x4 mfma16b(s16x4 a, s16x4 b, f32x4 c) {
#if __has_builtin(__builtin_amdgcn_mfma_f32_16x16x16bf16_1k)
    return __builtin_amdgcn_mfma_f32_16x16x16bf16_1k(a, b, c, 0, 0, 0);
#elif __has_builtin(__builtin_amdgcn_mfma_f32_16x16x16_bf16)
    return __builtin_amdgcn_mfma_f32_16x16x16_bf16(a, b, c, 0, 0, 0);
#else
    f32x4 d;
    asm volatile("s_nop 1\n\t"
                 "v_mfma_f32_16x16x16_bf16 %0, %1, %2, %3\n\t"
                 "s_nop 7\n\t"
                 "s_nop 7"
                 : "=v"(d) : "v"(a), "v"(b), "v"(c));
    return d;
#endif
}

__device__ __forceinline__ float exp2a(float x) {   // raw v_exp_f32 (input MUST
    float r;                                        // be VALU-produced, not MFMA)
    asm("v_exp_f32 %0, %1" : "=v"(r) : "v"(x));
    return r;
}
__device__ __forceinline__ float rcpa(float x) {    // raw v_rcp_f32 (same rule)
    float r;
    asm("v_rcp_f32 %0, %1" : "=v"(r) : "v"(x));
    return r;
}

__device__ __forceinline__ unsigned pk2(float a, float b) {   // 2xf32 -> packed bf16x2 (RNE)
    union { __hip_bfloat162 h; unsigned u; } c;
    float2 t; t.x = a; t.y = b;
    c.h = __float22bfloat162_rn(t);
    return c.u;
}
__device__ __forceinline__ s16x8 cvt8(const float* p) {  // 8 fp32 -> bf16x8
    union { unsigned u[4]; s16x8 v; } r;
    r.u[0] = pk2(p[0], p[1]); r.u[1] = pk2(p[2], p[3]);
    r.u[2] = pk2(p[4], p[5]); r.u[3] = pk2(p[6], p[7]);
    return r.v;
}
__device__ __forceinline__ s16x4 cvt4(const float* p) {  // 4 fp32 -> bf16x4
    union { unsigned u[2]; s16x4 v; } r;
    r.u[0] = pk2(p[0], p[1]); r.u[1] = pk2(p[2], p[3]);
    return r.v;
}

// LDS map (shorts).
//   ZNL: LN'd rows, slice per row-block (wl): wl*4096; row lr at
//        (lr>>4)*1024 + (lr&15)*64, gq-swizzled (r6-verified layout).
//   Per wave-group wg: KSH [256 pos][20 pad] at 16384+wg*9344, VT [16][264] after.
//   Reduction overlay (post-head-loop): f32 [256 rows][stride 68] at base 0
//   (69632 B <= 70144 B allocation; znl/KSH/VT all dead by then).
static constexpr int ZNL = 0;           // 4*4096 = 16384 sh
static constexpr int KSHB = 16384;      // + wg*9344
static constexpr int LDS_EL = 35072;    // 70144 B -> 2 blocks/CU at block 512

__global__ __launch_bounds__(512, 3)
void ka_all(const float* __restrict__ z, const float* __restrict__ ln_s,
            const float* __restrict__ ln_b, const float* __restrict__ Wq,
            const float* __restrict__ Wk, const float* __restrict__ Wv,
            const float* __restrict__ Wg, const float* __restrict__ bg,
            const float* __restrict__ Wo, const float* __restrict__ bo,
            float* __restrict__ out)
{
    __shared__ __align__(16) short lds[LDS_EL];
    const int tid = threadIdx.x, lane = tid & 63, w = tid >> 6;
    const int wg = w >> 2, wl = w & 3;             // group, wave-in-group
    const int n16 = lane & 15, quad = lane >> 4;
    const int bl = blockIdx.x;
    const int wsl = wl * 4096;                     // znl slice for this row-block
    const int wrows = wl * 64;                     // query rows wl*64..+64
    const int KSHg = KSHB + wg * 9344;
    const int VTg  = KSHg + 5120;

    // ---- LN once per row, by group 0 only (thread tid<256 = row bl*256+tid) ----
    if (w < 4) {
        float zn[64];
        const float4* zp4 = (const float4*)(z + ((size_t)bl * 256 + tid) * 64);
        #pragma unroll
        for (int gq = 0; gq < 16; ++gq) {
            float4 v4 = zp4[gq];
            zn[gq * 4 + 0] = v4.x; zn[gq * 4 + 1] = v4.y;
            zn[gq * 4 + 2] = v4.z; zn[gq * 4 + 3] = v4.w;
        }
        float mu = 0.f;
        #pragma unroll
        for (int k = 0; k < 64; ++k) mu += zn[k];
        mu *= (1.f / 64.f);
        float va = 0.f;
        #pragma unroll
        for (int k = 0; k < 64; ++k) { float d = zn[k] - mu; va += d * d; }
        const float rs = rsqrtf(va * (1.f / 64.f) + 1e-5f);
        #pragma unroll
        for (int k = 0; k < 64; ++k) zn[k] = (zn[k] - mu) * rs * ln_s[k] + ln_b[k];
        const int lr = lane;
        #pragma unroll
        for (int gq = 0; gq < 8; ++gq) {
            union { unsigned u[4]; s16x8 v; } pkv;
            pkv.u[0] = pk2(zn[gq * 8 + 0], zn[gq * 8 + 1]);
            pkv.u[1] = pk2(zn[gq * 8 + 2], zn[gq * 8 + 3]);
            pkv.u[2] = pk2(zn[gq * 8 + 4], zn[gq * 8 + 5]);
            pkv.u[3] = pk2(zn[gq * 8 + 6], zn[gq * 8 + 7]);
            *(s16x8*)&lds[ZNL + wsl + (lr >> 4) * 1024 + (lr & 15) * 64
                          + ((gq ^ (lr & 7)) * 8)] = pkv.v;
        }
    }
    __syncthreads();   // znl visible to both groups (read-only hereafter)

    constexpr float QS  = 0.25f;                            // 1/sqrt(Dh); log2e at exp
    constexpr float L2E = 1.44269504088896340736f;
    s16x4 ones4;                                            // bf16 1.0 x4
    {
        union { unsigned u[2]; s16x4 v; } c;
        c.u[0] = 0x3F803F80u; c.u[1] = 0x3F803F80u;
        ones4 = c.v;
    }

    f32x4 acc_out[4][4];                           // [qt][nt], over this group's heads
    #pragma unroll
    for (int qt = 0; qt < 4; ++qt)
        #pragma unroll
        for (int nt = 0; nt < 4; ++nt) acc_out[qt][nt] = {};

    for (int hh = 0; hh < 2; ++hh) {
        const int h = wg * 2 + hh;
        // ---- W head-slice frags (A for Q/K/G-transposed, B for V) ----
        s16x8 bq[2], bk[2], bv[2], bgf[2];
        #pragma unroll
        for (int ks = 0; ks < 2; ++ks) {
            size_t off = (size_t)(h * 16 + n16) * 64 + ks * 32 + quad * 8;
            bq[ks] = cvt8(Wq + off);  bk[ks] = cvt8(Wk + off);
            bv[ks] = cvt8(Wv + off);  bgf[ks] = cvt8(Wg + off);
        }
        const float4 bg4 = *(const float4*)(bg + h * 16 + quad * 4);

        float g4t[4][4];
        s16x4 qa4[4];                              // Q^T B-frags, in-register
        #pragma unroll
        for (int t = 0; t < 4; ++t) {              // projections for tile t
            s16x8 zn0 = *(const s16x8*)&lds[ZNL + wsl + t * 1024 + n16 * 64
                                            + ((quad ^ (n16 & 7)) * 8)];
            s16x8 zn1 = *(const s16x8*)&lds[ZNL + wsl + t * 1024 + n16 * 64
                                            + (((4 + quad) ^ (n16 & 7)) * 8)];
            f32x4 aq = {}, ak = {}, av = {}, ag = {};
            aq = MFMA16(bq[0], zn0, aq);  aq = MFMA16(bq[1], zn1, aq);   // Q^T
            ak = MFMA16(bk[0], zn0, ak);  ak = MFMA16(bk[1], zn1, ak);   // K^T
            ag = MFMA16(bgf[0], zn0, ag); ag = MFMA16(bgf[1], zn1, ag);  // G^T
            av = MFMA16(zn0, bv[0], av);  av = MFMA16(zn1, bv[1], av);   // V
            {   // Q^T (scaled) -> in-register B-frag: Q^T[dh=quad*4+r][i=n16]
                union { unsigned u[2]; s16x4 v; } q;
                q.u[0] = pk2(aq[0] * QS, aq[1] * QS);
                q.u[1] = pk2(aq[2] * QS, aq[3] * QS);
                qa4[t] = q.v;
            }
            {   // K^T -> KSHg[pos][dh] (stride 20, conflict-free b64 frags)
                uint2 p = {pk2(ak[0], ak[1]), pk2(ak[2], ak[3])};
                *(uint2*)&lds[KSHg + (wrows + t * 16 + n16) * 20 + quad * 4] = p;
            }
            {   // V -> VTg[dh][pos]
                uint2 p = {pk2(av[0], av[1]), pk2(av[2], av[3])};
                *(uint2*)&lds[VTg + n16 * 264 + (wrows + t * 16 + quad * 4)] = p;
            }
            #pragma unroll
            for (int r = 0; r < 4; ++r) {           // gate (pos=n16, dh=q*4+r)
                float x = ag[r] + bg4[r];           // VALU add absorbs MFMA hazard
                g4t[t][r] = rcpa(1.f + exp2a(x * -L2E));
            }
        }
        __syncthreads();   // KSHg/VTg for this head visible across the group

        // ---- attention (16x16x16): S^T = K@Q^T; P in-register; O^T = V^T@P^T;
        //      l = ones@P^T on the matrix pipe ----
        f32x4 o4[4], lacc[4];
        #pragma unroll
        for (int qt = 0; qt < 4; ++qt) { o4[qt] = {}; lacc[qt] = {}; }
        const int kbase = KSHg + n16 * 20 + quad * 4;   // + jt*320
        const int vbase = VTg + n16 * 264 + quad * 4;   // + jt*16
        for (int ch = 0; ch < 8; ++ch) {                // 32 keys per chunk
            #pragma unroll
            for (int jtl = 0; jtl < 2; ++jtl) {
                const int jt = ch * 2 + jtl;
                s16x4 kf = *(const s16x4*)&lds[kbase + jt * 320];
                s16x4 vf = *(const s16x4*)&lds[vbase + jt * 16];
                #pragma unroll
                for (int qt = 0; qt < 4; ++qt) {
                    f32x4 zc = {};
                    f32x4 s = mfma16b(kf, qa4[qt], zc);  // S^T: reg r = key q*4+r, col i=n16
                    // v_mul absorbs the MFMA->asm hazard.
                    float e0 = exp2a(s[0] * L2E), e1 = exp2a(s[1] * L2E);
                    float e2 = exp2a(s[2] * L2E), e3 = exp2a(s[3] * L2E);
                    union { unsigned u[2]; s16x4 v; } pb;
                    pb.u[0] = pk2(e0, e1); pb.u[1] = pk2(e2, e3);
                    o4[qt]   = mfma16b(vf, pb.v, o4[qt]);      // O^T: col=i, row=dh
                    lacc[qt] = mfma16b(ones4, pb.v, lacc[qt]); // l[i], all rows
                }
            }
        }

        // ---- per-head epilogue: gate+normalize -> bf16 -> Wo MFMA accumulate.
        // The gated O^T fragment (col=i=n16, row=dh=quad*4+r) IS the B-frag
        // B[k=dh][n=i] for out_tile = Wo_slice @ GO^T.
        s16x4 goB[4];
        #pragma unroll
        for (int qt = 0; qt < 4; ++qt) {
            const float l = (lacc[qt][0] + lacc[qt][1]) * 0.5f;  // VALU ops absorb hazard
            const float inv = rcpa(l);
            float g0 = g4t[qt][0] * o4[qt][0] * inv;
            float g1 = g4t[qt][1] * o4[qt][1] * inv;
            float g2 = g4t[qt][2] * o4[qt][2] * inv;
            float g3 = g4t[qt][3] * o4[qt][3] * inv;
            union { unsigned u[2]; s16x4 v; } pb;
            pb.u[0] = pk2(g0, g1); pb.u[1] = pk2(g2, g3);
            goB[qt] = pb.v;
        }
        #pragma unroll
        for (int nt = 0; nt < 4; ++nt) {
            // Wo A-frag: A[m=outd local=n16][k=dh=quad*4+u] for tile nt, head h
            s16x4 wof = cvt4(Wo + (size_t)(nt * 16 + n16) * 64 + h * 16 + quad * 4);
            #pragma unroll
            for (int qt = 0; qt < 4; ++qt)
                acc_out[qt][nt] = mfma16b(wof, goB[qt], acc_out[qt][nt]);
        }
        __syncthreads();   // KSHg/VTg reads done before next head's proj writes
                           // (final iteration: before the reduction overlay)
    }

    // ---- cross-group reduction in LDS (overlay; stride 68 floats = 2-way max) ----
    float* red = (float*)lds;
    if (wg == 1) {
        #pragma unroll
        for (int qt = 0; qt < 4; ++qt)
            #pragma unroll
            for (int nt = 0; nt < 4; ++nt)
                *(f32x4*)&red[(wrows + qt * 16 + n16) * 68 + nt * 16 + quad * 4] =
                    acc_out[qt][nt];   // ds_write of MFMA dest: compiler-fenced
    }
    __syncthreads();
    if (wg == 0) {
        #pragma unroll
        for (int nt = 0; nt < 4; ++nt) {
            const float4 b4 = *(const float4*)(bo + nt * 16 + quad * 4);
            f32x4 b4v; b4v[0] = b4.x; b4v[1] = b4.y; b4v[2] = b4.z; b4v[3] = b4.w;
            #pragma unroll
            for (int qt = 0; qt < 4; ++qt) {
                f32x4 o = *(f32x4*)&red[(wrows + qt * 16 + n16) * 68 + nt * 16 + quad * 4];
                f32x4 v = acc_out[qt][nt] + o + b4v;
                *(f32x4*)&out[((size_t)bl * 256 + wrows + qt * 16 + n16) * 64
                              + nt * 16 + quad * 4] = v;
            }
        }
    }
}

extern "C" void kernel_launch(void* const* d_in, const int* in_sizes, int n_in,
                              void* d_out, int out_size, void* d_ws, size_t ws_size,
                              hipStream_t stream) {
    const float* z  = (const float*)d_in[0];
    const float* ls = (const float*)d_in[1];
    const float* lb = (const float*)d_in[2];
    const float* Wq = (const float*)d_in[3];
    const float* Wk = (const float*)d_in[4];
    const float* Wv = (const float*)d_in[5];
    const float* Wg = (const float*)d_in[6];
    const float* bg = (const float*)d_in[7];
    const float* Wo = (const float*)d_in[8];
    const float* bo = (const float*)d_in[9];
    float* out = (float*)d_out;

    hipLaunchKernelGGL(ka_all, dim3(512), dim3(512), 0, stream,
                       z, ls, lb, Wq, Wk, Wv, Wg, bg, Wo, bo, out);
}